// Round 13
// baseline (242.007 us; speedup 1.0000x reference)
//
#include <hip/hip_runtime.h>
#include <hip/hip_bf16.h>

// ---------------------------------------------------------------------------
// MaskedSelfAttention: B=4, T=2048, C=1024, H=16 heads, D=64, causal.
// cast x->bf16, transpose W->bf16, fused QKV proj (128^2-tile pipelined
// bf16 MFMA GEMM), flash attention (swapped QK^T, fixed-reference softmax,
// native v_exp, V direct-from-global register dbuf, K LDS-staged, paired
// q-tiles), output proj.
// ---------------------------------------------------------------------------

typedef __attribute__((ext_vector_type(8))) short bhalf8;   // 8 x bf16
typedef __attribute__((ext_vector_type(4))) float f32x4;

#define BATCH 4
#define SEQ 2048
#define CDIM 1024
#define NHEAD 16
#define HDIM 64
#define MTOT (BATCH * SEQ)   // 8192
#define QSCALE 0.18033688011112042f   // 1/sqrt(64) * log2(e)

static __device__ inline unsigned short f2bf(float f) {
    unsigned int u = __float_as_uint(f);
    unsigned int r = (u + 0x7fffu + ((u >> 16) & 1u)) >> 16;
    return (unsigned short)r;
}
static __device__ inline float bf2f(unsigned short u) {
    return __uint_as_float(((unsigned int)u) << 16);
}
static __device__ inline f32x4 zero4() {
    f32x4 z = {0.f, 0.f, 0.f, 0.f};
    return z;
}
static __device__ inline f32x4 MFMA(bhalf8 a, bhalf8 b, f32x4 c) {
    return __builtin_amdgcn_mfma_f32_16x16x32_bf16(a, b, c, 0, 0, 0);
}
static __device__ inline void gload16(const void* g, void* l) {
    __builtin_amdgcn_global_load_lds(
        (const __attribute__((address_space(1))) unsigned int*)g,
        (__attribute__((address_space(3))) unsigned int*)l, 16, 0, 0);
}
// native v_exp_f32 (single instruction; libm exp2f w/o fast-math is guarded)
static __device__ inline float exp2n(float x) {
    return __builtin_amdgcn_exp2f(x);
}
// proven packed f32x2 -> bf16x2 (compiler lowers to the HW cvt path)
static __device__ inline unsigned int pkbf16(float lo, float hi) {
    union { __hip_bfloat162 h; unsigned int u; } c;
    c.h = __float22bfloat162_rn(make_float2(lo, hi));
    return c.u;
}

// ---------------------------------------------------------------------------
// cast x (fp32 [M][K]) -> bf16 (short) [M][K]
// ---------------------------------------------------------------------------
__global__ __launch_bounds__(256) void cast_x_kernel(const float* __restrict__ x,
                                                     short* __restrict__ o, int n8) {
    int i = blockIdx.x * 256 + threadIdx.x;
    if (i >= n8) return;
    const float4* xv = (const float4*)x;
    float4 a = xv[i * 2];
    float4 b = xv[i * 2 + 1];
    bhalf8 r;
    r[0] = (short)f2bf(a.x); r[1] = (short)f2bf(a.y);
    r[2] = (short)f2bf(a.z); r[3] = (short)f2bf(a.w);
    r[4] = (short)f2bf(b.x); r[5] = (short)f2bf(b.y);
    r[6] = (short)f2bf(b.z); r[7] = (short)f2bf(b.w);
    *(bhalf8*)(o + (size_t)i * 8) = r;
}

// ---------------------------------------------------------------------------
// transpose+cast 4 weight matrices: W fp32 [K][N] -> Wt bf16 [N][K]
// ---------------------------------------------------------------------------
__global__ __launch_bounds__(256) void wtrans_kernel(const float* __restrict__ W0,
                                                     const float* __restrict__ W1,
                                                     const float* __restrict__ W2,
                                                     const float* __restrict__ W3,
                                                     short* __restrict__ out) {
    __shared__ float t[32][33];
    const float* W = (blockIdx.z == 0) ? W0 : (blockIdx.z == 1) ? W1
                     : (blockIdx.z == 2) ? W2 : W3;
    short* o = out + (size_t)blockIdx.z * CDIM * CDIM;
    int n0 = blockIdx.x * 32, k0 = blockIdx.y * 32;
    int tx = threadIdx.x, ty = threadIdx.y;
    for (int j = 0; j < 4; ++j)
        t[ty + j * 8][tx] = W[(size_t)(k0 + ty + j * 8) * CDIM + n0 + tx];
    __syncthreads();
    for (int j = 0; j < 4; ++j)
        o[(size_t)(n0 + ty + j * 8) * CDIM + k0 + tx] = (short)f2bf(t[tx][ty + j * 8]);
}

// ---------------------------------------------------------------------------
// 128x128-tile GEMM, BK=32, K=1024, 256 threads (4 waves, 2x2), dbuf LDS,
// T3-min pipeline. MODE 0: fused QKV; MODE 1: O-proj. (unchanged)
// ---------------------------------------------------------------------------
template <int MODE, int GN>
__global__ __launch_bounds__(256) void gemm128(const short* __restrict__ A,
                                               const short* __restrict__ Bt,
                                               const float* __restrict__ b0,
                                               const float* __restrict__ b1,
                                               const float* __restrict__ b2,
                                               unsigned short* __restrict__ QKout,
                                               unsigned short* __restrict__ Vout,
                                               float* __restrict__ Fout) {
    __shared__ char lds[32768];
    char* AlB0 = lds;
    char* BlB0 = lds + 16384;

    const int tid = threadIdx.x, lane = tid & 63, w = tid >> 6;
    const int g = lane >> 4, t16 = lane & 15;
    const int wr = w >> 1, wc = w & 1;

    const int f = blockIdx.x;
    const int xcd = f & 7, i = f >> 3;
    const int mt = xcd * 8 + i / GN, nt = i % GN;
    const int tm = mt * 128, tn = nt * 128;
    const int part = tn >> 10;
    const int tnp = tn & 1023;

    const int c0 = tid, c1 = 256 + tid;
    const int r0 = c0 >> 2, r1 = c1 >> 2;
    const int k0c = (c0 & 3) ^ ((r0 >> 1) & 3);
    const int k1c = (c1 & 3) ^ ((r1 >> 1) & 3);
    const short* a0 = A + (size_t)(tm + r0) * 1024 + k0c * 8;
    const short* a1 = A + (size_t)(tm + r1) * 1024 + k1c * 8;
    const short* bp0 = Bt + (size_t)(tn + r0) * 1024 + k0c * 8;
    const short* bp1 = Bt + (size_t)(tn + r1) * 1024 + k1c * 8;

    int aoff[4], boff[4];
#pragma unroll
    for (int mi = 0; mi < 4; ++mi) {
        int row = wr * 64 + mi * 16 + t16;
        aoff[mi] = row * 64 + ((g ^ ((row >> 1) & 3)) << 4);
    }
#pragma unroll
    for (int ni = 0; ni < 4; ++ni) {
        int row = wc * 64 + ni * 16 + t16;
        boff[ni] = row * 64 + ((g ^ ((row >> 1) & 3)) << 4);
    }

    f32x4 acc[4][4];
#pragma unroll
    for (int mi = 0; mi < 4; ++mi)
#pragma unroll
        for (int ni = 0; ni < 4; ++ni) acc[mi][ni] = zero4();

#define STAGE(kt_, bb_)                                                   \
    do {                                                                  \
        int off_ = (kt_) * 32;                                            \
        char* al_ = AlB0 + (bb_) * 8192;                                  \
        char* bl_ = BlB0 + (bb_) * 8192;                                  \
        gload16(a0 + off_, al_ + tid * 16);                               \
        gload16(a1 + off_, al_ + 4096 + tid * 16);                        \
        gload16(bp0 + off_, bl_ + tid * 16);                              \
        gload16(bp1 + off_, bl_ + 4096 + tid * 16);                       \
    } while (0)

    STAGE(0, 0);
    __syncthreads();

#pragma unroll 2
    for (int kt = 0; kt < 32; ++kt) {
        const int buf = kt & 1;
        if (kt + 1 < 32) STAGE(kt + 1, buf ^ 1);
        const char* al = AlB0 + buf * 8192;
        const char* bl = BlB0 + buf * 8192;
        bhalf8 af[4], bfr[4];
#pragma unroll
        for (int mi = 0; mi < 4; ++mi) af[mi] = *(const bhalf8*)(al + aoff[mi]);
#pragma unroll
        for (int ni = 0; ni < 4; ++ni) bfr[ni] = *(const bhalf8*)(bl + boff[ni]);
        __builtin_amdgcn_s_setprio(1);
#pragma unroll
        for (int mi = 0; mi < 4; ++mi)
#pragma unroll
            for (int ni = 0; ni < 4; ++ni)
                acc[mi][ni] = MFMA(af[mi], bfr[ni], acc[mi][ni]);
        __builtin_amdgcn_s_setprio(0);
        __syncthreads();
    }
#undef STAGE

    if (MODE == 0 && part == 2) {
#pragma unroll
        for (int mi = 0; mi < 4; ++mi)
#pragma unroll
            for (int ni = 0; ni < 4; ++ni) {
                int col_l = wc * 64 + ni * 16 + t16;
                float bias = b2[tnp + col_l];
#pragma unroll
                for (int r = 0; r < 4; ++r) {
                    int row_l = wr * 64 + mi * 16 + g * 4 + r;
                    int byte = col_l * 256 + ((row_l * 2) ^ ((col_l & 7) << 4));
                    *(unsigned short*)(lds + byte) = f2bf(acc[mi][ni][r] + bias);
                }
            }
        __syncthreads();
#pragma unroll
        for (int p = 0; p < 8; ++p) {
            int lin = p * 4096 + tid * 16;
            int rv = lin >> 8;
            int inrow = lin & 255;
            int phys = rv * 256 + (inrow ^ ((rv & 7) << 4));
            bhalf8 val = *(const bhalf8*)(lds + phys);
            int n_g = tnp + rv;
            int hh = n_g >> 6, d = n_g & 63;
            int m = tm + (inrow >> 1);
            int bi = m >> 11, t0 = m & 2047;
            *(bhalf8*)(Vout + (((size_t)((bi * NHEAD + hh) * HDIM + d)) << 11) + t0) = val;
        }
    } else {
#pragma unroll
        for (int mi = 0; mi < 4; ++mi)
#pragma unroll
            for (int ni = 0; ni < 4; ++ni) {
                int col_l = wc * 64 + ni * 16 + t16;
                float bias = 0.f;
                if (MODE == 0) bias = (part == 0 ? b0 : b1)[tnp + col_l];
#pragma unroll
                for (int r = 0; r < 4; ++r) {
                    int row_l = wr * 64 + mi * 16 + g * 4 + r;
                    float v = acc[mi][ni][r] + bias;
                    if (MODE == 0 && part == 0) v *= QSCALE;
                    int byte = row_l * 256 + ((col_l * 2) ^ (((row_l >> 2) & 3) << 5));
                    *(unsigned short*)(lds + byte) = f2bf(v);
                }
            }
        __syncthreads();
#pragma unroll
        for (int p = 0; p < 8; ++p) {
            int lin = p * 4096 + tid * 16;
            int row_l = lin >> 8;
            int inrow = lin & 255;
            int phys = row_l * 256 + ((inrow & ~31) ^ (((row_l >> 2) & 3) << 5)) + (inrow & 31);
            bhalf8 val = *(const bhalf8*)(lds + phys);
            int col0 = inrow >> 1;
            int m = tm + row_l;
            if (MODE == 1) {
                int n_g = tn + col0;
                float* op = Fout + (size_t)m * 1024 + n_g;
                float4 o0, o1;
                o0.x = bf2f((unsigned short)val[0]) + b0[n_g + 0];
                o0.y = bf2f((unsigned short)val[1]) + b0[n_g + 1];
                o0.z = bf2f((unsigned short)val[2]) + b0[n_g + 2];
                o0.w = bf2f((unsigned short)val[3]) + b0[n_g + 3];
                o1.x = bf2f((unsigned short)val[4]) + b0[n_g + 4];
                o1.y = bf2f((unsigned short)val[5]) + b0[n_g + 5];
                o1.z = bf2f((unsigned short)val[6]) + b0[n_g + 6];
                o1.w = bf2f((unsigned short)val[7]) + b0[n_g + 7];
                *(float4*)(op) = o0;
                *(float4*)(op + 4) = o1;
            } else {
                int n_g = tnp + col0;
                int bi = m >> 11, t = m & 2047;
                int hh = n_g >> 6, d0 = n_g & 63;
                *(bhalf8*)(QKout +
                           (((size_t)((part * 64 + bi * NHEAD + hh) * SEQ + t)) << 6) + d0) = val;
            }
        }
    }
}

// ---------------------------------------------------------------------------
// Flash attention, causal. Swapped QK^T, fixed-reference softmax (native
// exp2), K LDS-staged (dbuf, shared by 4 waves), V register-dbuf direct from
// global (L2-resident), P pack via proven pkbf16, l via f32 sums + shfl
// (round-11-proven numerics). Paired 64-row q-tiles (33 kv-tiles/block),
// 1024 blocks, unified tile counter across the phase pair.
// ---------------------------------------------------------------------------
__global__ __launch_bounds__(256) void attn_kernel(const short* __restrict__ Q,
                                                   const short* __restrict__ K,
                                                   const short* __restrict__ V,
                                                   unsigned short* __restrict__ ctx) {
    __shared__ short Kl[2][64 * 64];   // 16 KB
    __shared__ short Pl[4][16 * 64];   // 8 KB (wave-private P)

    const int tid = threadIdx.x, lane = tid & 63, w = tid >> 6;
    const int g = lane >> 4, t16 = lane & 15;

    // 1024 blocks: XCD-chunk swizzle (128 consecutive per XCD = 8 full bh)
    int orig = blockIdx.x;
    int swz = (orig & 7) * 128 + (orig >> 3);
    const int bh = swz >> 4;      // 0..63
    const int sp = swz & 15;      // pair slot 0..15

    const short* Qh = Q + ((size_t)bh << 17);
    const short* Kh = K + ((size_t)bh << 17);
    const short* Vh = V + ((size_t)bh << 17);   // [D][T]

    // K staging: swizzled global source offsets + LDS dest (bytes)
    int koff[2], ldst[2];
#pragma unroll
    for (int it = 0; it < 2; ++it) {
        int c = it * 256 + tid;
        int srow = c >> 3;
        int dc = (c & 7) ^ (srow & 7);
        koff[it] = (srow << 6) + dc * 8;
        ldst[it] = it * 4096 + w * 1024;
    }
    // V fragment element offsets (B-operand, 16B contiguous in [D][T])
    int vel[4];
#pragma unroll
    for (int db = 0; db < 4; ++db) vel[db] = (db * 16 + t16) * 2048 + g * 8;

    const int b = bh >> 4, hh = bh & 15;
    const int swb = (t16 & 7) << 4;
    char* Pw = (char*)Pl[w];
    const int n0 = 32 - sp;    // tiles in phase 0 (qti = 31-sp)

#define STAGEK(kv_, bb_)                                                      \
    do {                                                                      \
        gload16(Kh + koff[0] + ((kv_) << 12), (char*)Kl[bb_] + ldst[0]);      \
        gload16(Kh + koff[1] + ((kv_) << 12), (char*)Kl[bb_] + ldst[1]);      \
    } while (0)

#define LOADV(VT, kv_)                                                        \
    do {                                                                      \
        const short* vp_ = Vh + ((kv_) << 6);                                 \
        _Pragma("unroll") for (int db = 0; db < 4; ++db) {                    \
            VT[db * 2]     = *(const bhalf8*)(vp_ + vel[db]);                 \
            VT[db * 2 + 1] = *(const bhalf8*)(vp_ + vel[db] + 32);            \
        }                                                                     \
    } while (0)

#define TILE(VT)                                                              \
    do {                                                                      \
        f32x4 lg[4];                                                          \
        __builtin_amdgcn_s_setprio(1);                                        \
        _Pragma("unroll") for (int cb = 0; cb < 4; ++cb) {                    \
            int s_ = cb * 16 + t16;                                           \
            int sw_ = (s_ & 7) << 4;                                          \
            const char* rowp = (const char*)Kl[buf] + s_ * 128;               \
            bhalf8 k0 = *(const bhalf8*)(rowp + ((g * 16) ^ sw_));            \
            bhalf8 k1 = *(const bhalf8*)(rowp + ((64 + g * 16) ^ sw_));       \
            f32x4 z = zero4();                                                \
            z = MFMA(k0, qf0, z);                                             \
            z = MFMA(k1, qf1, z);                                             \
            lg[cb] = z;                                                       \
        }                                                                     \
        __builtin_amdgcn_s_setprio(0);                                        \
        if (kv == qti) {                                                      \
            int rowl = w * 16 + t16;                                          \
            _Pragma("unroll") for (int cb = 0; cb < 4; ++cb) {                \
                int key0 = cb * 16 + g * 4;                                   \
                _Pragma("unroll") for (int r = 0; r < 4; ++r)                 \
                    if (key0 + r > rowl) lg[cb][r] = -1e30f;                  \
            }                                                                 \
        }                                                                     \
        {                                                                     \
            float s_ = 0.f;                                                   \
            int rowbyte = t16 * 128;                                          \
            _Pragma("unroll") for (int cb = 0; cb < 4; ++cb) {                \
                float e0 = exp2n(lg[cb][0]);                                  \
                float e1 = exp2n(lg[cb][1]);                                  \
                float e2 = exp2n(lg[cb][2]);                                  \
                float e3 = exp2n(lg[cb][3]);                                  \
                s_ += (e0 + e1) + (e2 + e3);                                  \
                uint2 wv;                                                     \
                wv.x = pkbf16(e0, e1);                                        \
                wv.y = pkbf16(e2, e3);                                        \
                int byte = (rowbyte + cb * 32 + g * 8) ^ swb;                 \
                *(uint2*)(Pw + byte) = wv;                                    \
            }                                                                 \
            l += s_;                                                          \
        }                                                                     \
        __builtin_amdgcn_s_setprio(1);                                        \
        _Pragma("unroll") for (int kk = 0; kk < 2; ++kk) {                    \
            int abyte = (t16 * 128 + kk * 64 + g * 16) ^ swb;                 \
            bhalf8 pa = *(const bhalf8*)(Pw + abyte);                         \
            _Pragma("unroll") for (int db = 0; db < 4; ++db)                  \
                acc[db] = MFMA(pa, VT[db * 2 + kk], acc[db]);                 \
        }                                                                     \
        __builtin_amdgcn_s_setprio(0);                                        \
    } while (0)

    bhalf8 va[8], vb[8];
    STAGEK(0, 0);
    LOADV(va, 0);
    int j = 0;   // global tile counter across both phases

    for (int ph = 0; ph < 2; ++ph) {
        const int qti = (ph == 0) ? (31 - sp) : sp;
        const int qbase = qti * 64;
        const int ntile = qti + 1;

        // Q B-frags: col=t16 -> q = qbase + w*16 + t16; k = kk*32+g*8+jj
        bhalf8 qf0, qf1;
        {
            const short* qp = Qh + ((size_t)(qbase + w * 16 + t16) << 6) + g * 8;
            qf0 = *(const bhalf8*)(qp);
            qf1 = *(const bhalf8*)(qp + 32);
        }

        f32x4 acc[4];   // [db]: q = g*4+r, d = db*16+t16
#pragma unroll
        for (int i = 0; i < 4; ++i) acc[i] = zero4();
        float l = 0.f;  // t16-layout: q = t16

        __syncthreads();   // staged K tile ready (drains vmcnt)

        for (int kv = 0; kv < ntile; ++kv, ++j) {
            const int buf = j & 1;
            int jn = j + 1;
            int kvn = (jn < n0) ? jn : jn - n0;
            bool pre = jn < 33;
            if (pre) STAGEK(kvn, buf ^ 1);
            if (j & 1) {
                if (pre) LOADV(va, kvn);
                TILE(vb);
            } else {
                if (pre) LOADV(vb, kvn);
                TILE(va);
            }
            __syncthreads();
        }

        // ---- finalize l (2 shfl), broadcast 1/l, write ctx ----
        float lt = l;
        lt += __shfl_xor(lt, 16, 64);
        lt += __shfl_xor(lt, 32, 64);
        float linv = 1.f / lt;
#pragma unroll
        for (int r = 0; r < 4; ++r) {
            float inv = __shfl(linv, g * 4 + r, 64);
            int t = qbase + w * 16 + g * 4 + r;
            size_t rowoff = (((size_t)(b * SEQ + t)) << 10) + hh * 64;
#pragma unroll
            for (int db = 0; db < 4; ++db)
                ctx[rowoff + db * 16 + t16] = f2bf(acc[db][r] * inv);
        }
    }
#undef TILE
#undef LOADV
#undef STAGEK
}

// ---------------------------------------------------------------------------
// launch
// ---------------------------------------------------------------------------
extern "C" void kernel_launch(void* const* d_in, const int* in_sizes, int n_in,
                              void* d_out, int out_size, void* d_ws, size_t ws_size,
                              hipStream_t stream) {
    const float* x  = (const float*)d_in[0];
    const float* Wq = (const float*)d_in[1];
    const float* bq = (const float*)d_in[2];
    const float* Wk = (const float*)d_in[3];
    const float* bk = (const float*)d_in[4];
    const float* Wv = (const float*)d_in[5];
    const float* bv = (const float*)d_in[6];
    const float* Wo = (const float*)d_in[7];
    const float* bo = (const float*)d_in[8];

    char* ws = (char*)d_ws;
    short* x16 = (short*)(ws);                                // 16 MB
    short* Wt  = (short*)(ws + (size_t)16 * 1024 * 1024);     // q,k,v,o 2MB each
    short* Wot = Wt + (size_t)3 * CDIM * CDIM;
    short* Qb  = (short*)(ws + (size_t)24 * 1024 * 1024);     // 32 MB Q||K
    short* Vb  = (short*)(ws + (size_t)56 * 1024 * 1024);     // 16 MB [BH][D][T]
    short* Ctx = (short*)(ws + (size_t)72 * 1024 * 1024);     // 16 MB [M][C]

    cast_x_kernel<<<dim3(MTOT * CDIM / 8 / 256), dim3(256), 0, stream>>>(
        x, x16, MTOT * CDIM / 8);
    wtrans_kernel<<<dim3(32, 32, 4), dim3(32, 8), 0, stream>>>(Wq, Wk, Wv, Wo, Wt);

    // fused QKV projection: N = 3072 (Wq||Wk||Wv rows), 1536 blocks (6/CU)
    gemm128<0, 24><<<dim3(1536), dim3(256), 0, stream>>>(
        x16, Wt, bq, bk, bv, (unsigned short*)Qb, (unsigned short*)Vb, nullptr);

    // attention: 1024 paired blocks (K part = Qb + 64*SEQ*HDIM)
    attn_kernel<<<dim3(1024), dim3(256), 0, stream>>>(
        Qb, Qb + (size_t)64 * SEQ * HDIM, Vb, (unsigned short*)Ctx);

    // output projection -> fp32 d_out, 512 blocks (2/CU)
    gemm128<1, 8><<<dim3(512), dim3(256), 0, stream>>>(
        Ctx, Wot, bo, nullptr, nullptr, nullptr, nullptr, (float*)d_out);
}

// Round 14
// 182.007 us; speedup vs baseline: 1.3297x; 1.3297x over previous
//
#include <hip/hip_runtime.h>
#include <hip/hip_bf16.h>

// ---------------------------------------------------------------------------
// MaskedSelfAttention: B=4, T=2048, C=1024, H=16 heads, D=64, causal.
// cast x->bf16, transpose W->bf16, fused QKV proj (128^2-tile pipelined
// bf16 MFMA GEMM), flash attention (swapped QK^T, fixed-reference softmax
// with native v_exp_f32, K+V LDS-staged, l via ones-MFMA, paired q-tiles),
// output proj.
// ---------------------------------------------------------------------------

typedef __attribute__((ext_vector_type(8))) short bhalf8;   // 8 x bf16
typedef __attribute__((ext_vector_type(4))) float f32x4;

#define BATCH 4
#define SEQ 2048
#define CDIM 1024
#define NHEAD 16
#define HDIM 64
#define MTOT (BATCH * SEQ)   // 8192
#define QSCALE 0.18033688011112042f   // 1/sqrt(64) * log2(e)

static __device__ inline unsigned short f2bf(float f) {
    unsigned int u = __float_as_uint(f);
    unsigned int r = (u + 0x7fffu + ((u >> 16) & 1u)) >> 16;
    return (unsigned short)r;
}
static __device__ inline float bf2f(unsigned short u) {
    return __uint_as_float(((unsigned int)u) << 16);
}
static __device__ inline f32x4 zero4() {
    f32x4 z = {0.f, 0.f, 0.f, 0.f};
    return z;
}
static __device__ inline f32x4 MFMA(bhalf8 a, bhalf8 b, f32x4 c) {
    return __builtin_amdgcn_mfma_f32_16x16x32_bf16(a, b, c, 0, 0, 0);
}
static __device__ inline void gload16(const void* g, void* l) {
    __builtin_amdgcn_global_load_lds(
        (const __attribute__((address_space(1))) unsigned int*)g,
        (__attribute__((address_space(3))) unsigned int*)l, 16, 0, 0);
}
// native v_exp_f32 (single instruction; libm exp2f w/o fast-math is guarded)
static __device__ inline float exp2n(float x) {
    return __builtin_amdgcn_exp2f(x);
}
// proven packed f32x2 -> bf16x2 (compiler lowers to the HW cvt path)
static __device__ inline unsigned int pkbf16(float lo, float hi) {
    union { __hip_bfloat162 h; unsigned int u; } c;
    c.h = __float22bfloat162_rn(make_float2(lo, hi));
    return c.u;
}

// ---------------------------------------------------------------------------
// cast x (fp32 [M][K]) -> bf16 (short) [M][K]
// ---------------------------------------------------------------------------
__global__ __launch_bounds__(256) void cast_x_kernel(const float* __restrict__ x,
                                                     short* __restrict__ o, int n8) {
    int i = blockIdx.x * 256 + threadIdx.x;
    if (i >= n8) return;
    const float4* xv = (const float4*)x;
    float4 a = xv[i * 2];
    float4 b = xv[i * 2 + 1];
    bhalf8 r;
    r[0] = (short)f2bf(a.x); r[1] = (short)f2bf(a.y);
    r[2] = (short)f2bf(a.z); r[3] = (short)f2bf(a.w);
    r[4] = (short)f2bf(b.x); r[5] = (short)f2bf(b.y);
    r[6] = (short)f2bf(b.z); r[7] = (short)f2bf(b.w);
    *(bhalf8*)(o + (size_t)i * 8) = r;
}

// ---------------------------------------------------------------------------
// transpose+cast 4 weight matrices: W fp32 [K][N] -> Wt bf16 [N][K]
// ---------------------------------------------------------------------------
__global__ __launch_bounds__(256) void wtrans_kernel(const float* __restrict__ W0,
                                                     const float* __restrict__ W1,
                                                     const float* __restrict__ W2,
                                                     const float* __restrict__ W3,
                                                     short* __restrict__ out) {
    __shared__ float t[32][33];
    const float* W = (blockIdx.z == 0) ? W0 : (blockIdx.z == 1) ? W1
                     : (blockIdx.z == 2) ? W2 : W3;
    short* o = out + (size_t)blockIdx.z * CDIM * CDIM;
    int n0 = blockIdx.x * 32, k0 = blockIdx.y * 32;
    int tx = threadIdx.x, ty = threadIdx.y;
    for (int j = 0; j < 4; ++j)
        t[ty + j * 8][tx] = W[(size_t)(k0 + ty + j * 8) * CDIM + n0 + tx];
    __syncthreads();
    for (int j = 0; j < 4; ++j)
        o[(size_t)(n0 + ty + j * 8) * CDIM + k0 + tx] = (short)f2bf(t[tx][ty + j * 8]);
}

// ---------------------------------------------------------------------------
// 128x128-tile GEMM, BK=32, K=1024, 256 threads (4 waves, 2x2), dbuf LDS,
// T3-min pipeline. MODE 0: fused QKV; MODE 1: O-proj. (unchanged)
// ---------------------------------------------------------------------------
template <int MODE, int GN>
__global__ __launch_bounds__(256) void gemm128(const short* __restrict__ A,
                                               const short* __restrict__ Bt,
                                               const float* __restrict__ b0,
                                               const float* __restrict__ b1,
                                               const float* __restrict__ b2,
                                               unsigned short* __restrict__ QKout,
                                               unsigned short* __restrict__ Vout,
                                               float* __restrict__ Fout) {
    __shared__ char lds[32768];
    char* AlB0 = lds;
    char* BlB0 = lds + 16384;

    const int tid = threadIdx.x, lane = tid & 63, w = tid >> 6;
    const int g = lane >> 4, t16 = lane & 15;
    const int wr = w >> 1, wc = w & 1;

    const int f = blockIdx.x;
    const int xcd = f & 7, i = f >> 3;
    const int mt = xcd * 8 + i / GN, nt = i % GN;
    const int tm = mt * 128, tn = nt * 128;
    const int part = tn >> 10;
    const int tnp = tn & 1023;

    const int c0 = tid, c1 = 256 + tid;
    const int r0 = c0 >> 2, r1 = c1 >> 2;
    const int k0c = (c0 & 3) ^ ((r0 >> 1) & 3);
    const int k1c = (c1 & 3) ^ ((r1 >> 1) & 3);
    const short* a0 = A + (size_t)(tm + r0) * 1024 + k0c * 8;
    const short* a1 = A + (size_t)(tm + r1) * 1024 + k1c * 8;
    const short* bp0 = Bt + (size_t)(tn + r0) * 1024 + k0c * 8;
    const short* bp1 = Bt + (size_t)(tn + r1) * 1024 + k1c * 8;

    int aoff[4], boff[4];
#pragma unroll
    for (int mi = 0; mi < 4; ++mi) {
        int row = wr * 64 + mi * 16 + t16;
        aoff[mi] = row * 64 + ((g ^ ((row >> 1) & 3)) << 4);
    }
#pragma unroll
    for (int ni = 0; ni < 4; ++ni) {
        int row = wc * 64 + ni * 16 + t16;
        boff[ni] = row * 64 + ((g ^ ((row >> 1) & 3)) << 4);
    }

    f32x4 acc[4][4];
#pragma unroll
    for (int mi = 0; mi < 4; ++mi)
#pragma unroll
        for (int ni = 0; ni < 4; ++ni) acc[mi][ni] = zero4();

#define STAGE(kt_, bb_)                                                   \
    do {                                                                  \
        int off_ = (kt_) * 32;                                            \
        char* al_ = AlB0 + (bb_) * 8192;                                  \
        char* bl_ = BlB0 + (bb_) * 8192;                                  \
        gload16(a0 + off_, al_ + tid * 16);                               \
        gload16(a1 + off_, al_ + 4096 + tid * 16);                        \
        gload16(bp0 + off_, bl_ + tid * 16);                              \
        gload16(bp1 + off_, bl_ + 4096 + tid * 16);                       \
    } while (0)

    STAGE(0, 0);
    __syncthreads();

#pragma unroll 2
    for (int kt = 0; kt < 32; ++kt) {
        const int buf = kt & 1;
        if (kt + 1 < 32) STAGE(kt + 1, buf ^ 1);
        const char* al = AlB0 + buf * 8192;
        const char* bl = BlB0 + buf * 8192;
        bhalf8 af[4], bfr[4];
#pragma unroll
        for (int mi = 0; mi < 4; ++mi) af[mi] = *(const bhalf8*)(al + aoff[mi]);
#pragma unroll
        for (int ni = 0; ni < 4; ++ni) bfr[ni] = *(const bhalf8*)(bl + boff[ni]);
        __builtin_amdgcn_s_setprio(1);
#pragma unroll
        for (int mi = 0; mi < 4; ++mi)
#pragma unroll
            for (int ni = 0; ni < 4; ++ni)
                acc[mi][ni] = MFMA(af[mi], bfr[ni], acc[mi][ni]);
        __builtin_amdgcn_s_setprio(0);
        __syncthreads();
    }
#undef STAGE

    if (MODE == 0 && part == 2) {
#pragma unroll
        for (int mi = 0; mi < 4; ++mi)
#pragma unroll
            for (int ni = 0; ni < 4; ++ni) {
                int col_l = wc * 64 + ni * 16 + t16;
                float bias = b2[tnp + col_l];
#pragma unroll
                for (int r = 0; r < 4; ++r) {
                    int row_l = wr * 64 + mi * 16 + g * 4 + r;
                    int byte = col_l * 256 + ((row_l * 2) ^ ((col_l & 7) << 4));
                    *(unsigned short*)(lds + byte) = f2bf(acc[mi][ni][r] + bias);
                }
            }
        __syncthreads();
#pragma unroll
        for (int p = 0; p < 8; ++p) {
            int lin = p * 4096 + tid * 16;
            int rv = lin >> 8;
            int inrow = lin & 255;
            int phys = rv * 256 + (inrow ^ ((rv & 7) << 4));
            bhalf8 val = *(const bhalf8*)(lds + phys);
            int n_g = tnp + rv;
            int hh = n_g >> 6, d = n_g & 63;
            int m = tm + (inrow >> 1);
            int bi = m >> 11, t0 = m & 2047;
            *(bhalf8*)(Vout + (((size_t)((bi * NHEAD + hh) * HDIM + d)) << 11) + t0) = val;
        }
    } else {
#pragma unroll
        for (int mi = 0; mi < 4; ++mi)
#pragma unroll
            for (int ni = 0; ni < 4; ++ni) {
                int col_l = wc * 64 + ni * 16 + t16;
                float bias = 0.f;
                if (MODE == 0) bias = (part == 0 ? b0 : b1)[tnp + col_l];
#pragma unroll
                for (int r = 0; r < 4; ++r) {
                    int row_l = wr * 64 + mi * 16 + g * 4 + r;
                    float v = acc[mi][ni][r] + bias;
                    if (MODE == 0 && part == 0) v *= QSCALE;
                    int byte = row_l * 256 + ((col_l * 2) ^ (((row_l >> 2) & 3) << 5));
                    *(unsigned short*)(lds + byte) = f2bf(v);
                }
            }
        __syncthreads();
#pragma unroll
        for (int p = 0; p < 8; ++p) {
            int lin = p * 4096 + tid * 16;
            int row_l = lin >> 8;
            int inrow = lin & 255;
            int phys = row_l * 256 + ((inrow & ~31) ^ (((row_l >> 2) & 3) << 5)) + (inrow & 31);
            bhalf8 val = *(const bhalf8*)(lds + phys);
            int col0 = inrow >> 1;
            int m = tm + row_l;
            if (MODE == 1) {
                int n_g = tn + col0;
                float* op = Fout + (size_t)m * 1024 + n_g;
                float4 o0, o1;
                o0.x = bf2f((unsigned short)val[0]) + b0[n_g + 0];
                o0.y = bf2f((unsigned short)val[1]) + b0[n_g + 1];
                o0.z = bf2f((unsigned short)val[2]) + b0[n_g + 2];
                o0.w = bf2f((unsigned short)val[3]) + b0[n_g + 3];
                o1.x = bf2f((unsigned short)val[4]) + b0[n_g + 4];
                o1.y = bf2f((unsigned short)val[5]) + b0[n_g + 5];
                o1.z = bf2f((unsigned short)val[6]) + b0[n_g + 6];
                o1.w = bf2f((unsigned short)val[7]) + b0[n_g + 7];
                *(float4*)(op) = o0;
                *(float4*)(op + 4) = o1;
            } else {
                int n_g = tnp + col0;
                int bi = m >> 11, t = m & 2047;
                int hh = n_g >> 6, d0 = n_g & 63;
                *(bhalf8*)(QKout +
                           (((size_t)((part * 64 + bi * NHEAD + hh) * SEQ + t)) << 6) + d0) = val;
            }
        }
    }
}

// ---------------------------------------------------------------------------
// Flash attention, causal, double-buffered, swapped QK^T, fixed-reference
// softmax (P = exp2(lg) via native v_exp_f32). K+V LDS-staged (round-11
// structure). l via ones-MFMA: accl = MFMA(P_frag, ones, accl) gives the
// row-sum in the SAME layout as the PV accumulator (no shuffles at all).
// 64-row q-tiles paired s <-> 31-s (33 kv-tiles/block), 1024 blocks (4/CU).
// ---------------------------------------------------------------------------
__global__ __launch_bounds__(256) void attn_kernel(const short* __restrict__ Q,
                                                   const short* __restrict__ K,
                                                   const short* __restrict__ V,
                                                   unsigned short* __restrict__ ctx) {
    __shared__ short Kl[2][64 * 64];
    __shared__ short Vl[2][64 * 64];
    __shared__ short Pl[4][16 * 64];

    const int tid = threadIdx.x, lane = tid & 63, w = tid >> 6;
    const int g = lane >> 4, t16 = lane & 15;

    // 1024 blocks: XCD-chunk swizzle (128 consecutive per XCD = 8 full bh)
    int orig = blockIdx.x;
    int swz = (orig & 7) * 128 + (orig >> 3);
    const int bh = swz >> 4;      // 0..63
    const int sp = swz & 15;      // pair slot 0..15

    const short* Qh = Q + ((size_t)bh << 17);
    const short* Kh = K + ((size_t)bh << 17);
    const short* Vh = V + ((size_t)bh << 17);   // [D][T]

    // hoisted swizzled staging offsets (shorts) + LDS dest offsets (bytes)
    int koff[2], voff[2], ldst[2];
#pragma unroll
    for (int it = 0; it < 2; ++it) {
        int c = it * 256 + tid;
        int srow = c >> 3;
        int dc = (c & 7) ^ (srow & 7);
        koff[it] = (srow << 6) + dc * 8;
        voff[it] = (srow << 11) + dc * 8;
        ldst[it] = it * 4096 + w * 1024;
    }

#define STAGE(kv_, bb_)                                                       \
    do {                                                                      \
        gload16(Kh + koff[0] + ((kv_) << 12), (char*)Kl[bb_] + ldst[0]);      \
        gload16(Kh + koff[1] + ((kv_) << 12), (char*)Kl[bb_] + ldst[1]);      \
        gload16(Vh + voff[0] + ((kv_) << 6), (char*)Vl[bb_] + ldst[0]);       \
        gload16(Vh + voff[1] + ((kv_) << 6), (char*)Vl[bb_] + ldst[1]);       \
    } while (0)

    const int b = bh >> 4, hh = bh & 15;
    const int swb = (t16 & 7) << 4;

    bhalf8 ones;
#pragma unroll
    for (int q = 0; q < 8; ++q) ones[q] = (short)0x3F80;   // bf16 1.0

    int buf = 0;
    STAGE(0, 0);   // phase-0 tile 0

    for (int ph = 0; ph < 2; ++ph) {
        const int qti = (ph == 0) ? (31 - sp) : sp;
        const int qbase = qti * 64;
        const int ntile = qti + 1;

        // Q B-frags: col=t16 -> q = qbase + w*16 + t16; k = kk*32+g*8+j
        bhalf8 qf0, qf1;
        {
            const short* qp = Qh + ((size_t)(qbase + w * 16 + t16) << 6) + g * 8;
            qf0 = *(const bhalf8*)(qp);
            qf1 = *(const bhalf8*)(qp + 32);
        }

        f32x4 acc[4];   // [db]: q = g*4+r, d = db*16+t16
        f32x4 accl;     // l row-sums: q = g*4+r (all 16 cols identical)
#pragma unroll
        for (int i = 0; i < 4; ++i) acc[i] = zero4();
        accl = zero4();

        __syncthreads();   // staged tile 0 ready (drains vmcnt)

        for (int kv = 0; kv < ntile; ++kv) {
            if (kv + 1 < ntile) STAGE(kv + 1, buf ^ 1);

            // ---- QK^T (swapped): lg[cb], key=kv*64+cb*16+g*4+r, q=t16 ----
            f32x4 lg[4];
            __builtin_amdgcn_s_setprio(1);
#pragma unroll
            for (int cb = 0; cb < 4; ++cb) {
                int s = cb * 16 + t16;
                int sw = (s & 7) << 4;
                const char* rowp = (const char*)Kl[buf] + s * 128;
                bhalf8 k0 = *(const bhalf8*)(rowp + ((g * 16) ^ sw));
                bhalf8 k1 = *(const bhalf8*)(rowp + ((64 + g * 16) ^ sw));
                f32x4 z = zero4();
                z = MFMA(k0, qf0, z);
                z = MFMA(k1, qf1, z);
                lg[cb] = z;
            }
            __builtin_amdgcn_s_setprio(0);

            // ---- causal mask (diag tile only) ----
            if (kv == qti) {
                int rowl = w * 16 + t16;
#pragma unroll
                for (int cb = 0; cb < 4; ++cb) {
                    int key0 = cb * 16 + g * 4;
#pragma unroll
                    for (int r = 0; r < 4; ++r)
                        if (key0 + r > rowl) lg[cb][r] = -1e30f;
                }
            }

            // ---- P = exp2(lg) (fixed reference, native v_exp_f32) ----
            {
                int rowbyte = t16 * 128;
#pragma unroll
                for (int cb = 0; cb < 4; ++cb) {
                    float e0 = exp2n(lg[cb][0]);
                    float e1 = exp2n(lg[cb][1]);
                    float e2 = exp2n(lg[cb][2]);
                    float e3 = exp2n(lg[cb][3]);
                    uint2 wv;
                    wv.x = pkbf16(e0, e1);
                    wv.y = pkbf16(e2, e3);
                    int byte = (rowbyte + cb * 32 + g * 8) ^ swb;
                    *(uint2*)((char*)Pl[w] + byte) = wv;
                }
            }

            // ---- PV: acc += P @ V ; accl += P @ ones (row-sum l) ----
            __builtin_amdgcn_s_setprio(1);
#pragma unroll
            for (int kk = 0; kk < 2; ++kk) {
                bhalf8 vf[4];
#pragma unroll
                for (int db = 0; db < 4; ++db) {
                    int d = db * 16 + t16;
                    int vbyte = d * 128 + ((kk * 64 + g * 16) ^ ((d & 7) << 4));
                    vf[db] = *(const bhalf8*)((const char*)Vl[buf] + vbyte);
                }
                int abyte = (t16 * 128 + kk * 64 + g * 16) ^ swb;
                bhalf8 pa = *(const bhalf8*)((const char*)Pl[w] + abyte);
                accl = MFMA(pa, ones, accl);
#pragma unroll
                for (int db = 0; db < 4; ++db)
                    acc[db] = MFMA(pa, vf[db], acc[db]);
            }
            __builtin_amdgcn_s_setprio(0);

            __syncthreads();
            buf ^= 1;
        }

        // prefetch phase-1 tile 0 into the free buffer (hides under epilogue)
        if (ph == 0) STAGE(0, buf);

        // ---- normalize (l in-lane, same layout as acc) + write ctx ----
#pragma unroll
        for (int r = 0; r < 4; ++r) {
            float inv = 1.f / accl[r];
            int t = qbase + w * 16 + g * 4 + r;
            size_t rowoff = (((size_t)(b * SEQ + t)) << 10) + hh * 64;
#pragma unroll
            for (int db = 0; db < 4; ++db)
                ctx[rowoff + db * 16 + t16] = f2bf(acc[db][r] * inv);
        }
    }
#undef STAGE
}

// ---------------------------------------------------------------------------
// launch
// ---------------------------------------------------------------------------
extern "C" void kernel_launch(void* const* d_in, const int* in_sizes, int n_in,
                              void* d_out, int out_size, void* d_ws, size_t ws_size,
                              hipStream_t stream) {
    const float* x  = (const float*)d_in[0];
    const float* Wq = (const float*)d_in[1];
    const float* bq = (const float*)d_in[2];
    const float* Wk = (const float*)d_in[3];
    const float* bk = (const float*)d_in[4];
    const float* Wv = (const float*)d_in[5];
    const float* bv = (const float*)d_in[6];
    const float* Wo = (const float*)d_in[7];
    const float* bo = (const float*)d_in[8];

    char* ws = (char*)d_ws;
    short* x16 = (short*)(ws);                                // 16 MB
    short* Wt  = (short*)(ws + (size_t)16 * 1024 * 1024);     // q,k,v,o 2MB each
    short* Wot = Wt + (size_t)3 * CDIM * CDIM;
    short* Qb  = (short*)(ws + (size_t)24 * 1024 * 1024);     // 32 MB Q||K
    short* Vb  = (short*)(ws + (size_t)56 * 1024 * 1024);     // 16 MB [BH][D][T]
    short* Ctx = (short*)(ws + (size_t)72 * 1024 * 1024);     // 16 MB [M][C]

    cast_x_kernel<<<dim3(MTOT * CDIM / 8 / 256), dim3(256), 0, stream>>>(
        x, x16, MTOT * CDIM / 8);
    wtrans_kernel<<<dim3(32, 32, 4), dim3(32, 8), 0, stream>>>(Wq, Wk, Wv, Wo, Wt);

    // fused QKV projection: N = 3072 (Wq||Wk||Wv rows), 1536 blocks (6/CU)
    gemm128<0, 24><<<dim3(1536), dim3(256), 0, stream>>>(
        x16, Wt, bq, bk, bv, (unsigned short*)Qb, (unsigned short*)Vb, nullptr);

    // attention: 1024 paired blocks (K part = Qb + 64*SEQ*HDIM)
    attn_kernel<<<dim3(1024), dim3(256), 0, stream>>>(
        Qb, Qb + (size_t)64 * SEQ * HDIM, Vb, (unsigned short*)Ctx);

    // output projection -> fp32 d_out, 512 blocks (2/CU)
    gemm128<1, 8><<<dim3(512), dim3(256), 0, stream>>>(
        Ctx, Wot, bo, nullptr, nullptr, nullptr, nullptr, (float*)d_out);
}

// Round 15
// 179.501 us; speedup vs baseline: 1.3482x; 1.0140x over previous
//
#include <hip/hip_runtime.h>
#include <hip/hip_bf16.h>

// ---------------------------------------------------------------------------
// MaskedSelfAttention: B=4, T=2048, C=1024, H=16 heads, D=64, causal.
// cast x->bf16, transpose W->bf16, fused QKV proj (128^2-tile pipelined
// bf16 MFMA GEMM), flash attention (swapped QK^T, fixed-reference softmax
// with native v_exp_f32, K+V LDS-staged with BRANCH-STATIC double buffers
// (loop-invariant LDS addresses), l via ones-MFMA, paired q-tiles),
// output proj.
// ---------------------------------------------------------------------------

typedef __attribute__((ext_vector_type(8))) short bhalf8;   // 8 x bf16
typedef __attribute__((ext_vector_type(4))) float f32x4;

#define BATCH 4
#define SEQ 2048
#define CDIM 1024
#define NHEAD 16
#define HDIM 64
#define MTOT (BATCH * SEQ)   // 8192
#define QSCALE 0.18033688011112042f   // 1/sqrt(64) * log2(e)

static __device__ inline unsigned short f2bf(float f) {
    unsigned int u = __float_as_uint(f);
    unsigned int r = (u + 0x7fffu + ((u >> 16) & 1u)) >> 16;
    return (unsigned short)r;
}
static __device__ inline float bf2f(unsigned short u) {
    return __uint_as_float(((unsigned int)u) << 16);
}
static __device__ inline f32x4 zero4() {
    f32x4 z = {0.f, 0.f, 0.f, 0.f};
    return z;
}
static __device__ inline f32x4 MFMA(bhalf8 a, bhalf8 b, f32x4 c) {
    return __builtin_amdgcn_mfma_f32_16x16x32_bf16(a, b, c, 0, 0, 0);
}
static __device__ inline void gload16(const void* g, void* l) {
    __builtin_amdgcn_global_load_lds(
        (const __attribute__((address_space(1))) unsigned int*)g,
        (__attribute__((address_space(3))) unsigned int*)l, 16, 0, 0);
}
// native v_exp_f32 (single instruction; libm exp2f w/o fast-math is guarded)
static __device__ inline float exp2n(float x) {
    return __builtin_amdgcn_exp2f(x);
}
// proven packed f32x2 -> bf16x2 (compiler lowers to the HW cvt path)
static __device__ inline unsigned int pkbf16(float lo, float hi) {
    union { __hip_bfloat162 h; unsigned int u; } c;
    c.h = __float22bfloat162_rn(make_float2(lo, hi));
    return c.u;
}

// ---------------------------------------------------------------------------
// cast x (fp32 [M][K]) -> bf16 (short) [M][K]
// ---------------------------------------------------------------------------
__global__ __launch_bounds__(256) void cast_x_kernel(const float* __restrict__ x,
                                                     short* __restrict__ o, int n8) {
    int i = blockIdx.x * 256 + threadIdx.x;
    if (i >= n8) return;
    const float4* xv = (const float4*)x;
    float4 a = xv[i * 2];
    float4 b = xv[i * 2 + 1];
    bhalf8 r;
    r[0] = (short)f2bf(a.x); r[1] = (short)f2bf(a.y);
    r[2] = (short)f2bf(a.z); r[3] = (short)f2bf(a.w);
    r[4] = (short)f2bf(b.x); r[5] = (short)f2bf(b.y);
    r[6] = (short)f2bf(b.z); r[7] = (short)f2bf(b.w);
    *(bhalf8*)(o + (size_t)i * 8) = r;
}

// ---------------------------------------------------------------------------
// transpose+cast 4 weight matrices: W fp32 [K][N] -> Wt bf16 [N][K]
// ---------------------------------------------------------------------------
__global__ __launch_bounds__(256) void wtrans_kernel(const float* __restrict__ W0,
                                                     const float* __restrict__ W1,
                                                     const float* __restrict__ W2,
                                                     const float* __restrict__ W3,
                                                     short* __restrict__ out) {
    __shared__ float t[32][33];
    const float* W = (blockIdx.z == 0) ? W0 : (blockIdx.z == 1) ? W1
                     : (blockIdx.z == 2) ? W2 : W3;
    short* o = out + (size_t)blockIdx.z * CDIM * CDIM;
    int n0 = blockIdx.x * 32, k0 = blockIdx.y * 32;
    int tx = threadIdx.x, ty = threadIdx.y;
    for (int j = 0; j < 4; ++j)
        t[ty + j * 8][tx] = W[(size_t)(k0 + ty + j * 8) * CDIM + n0 + tx];
    __syncthreads();
    for (int j = 0; j < 4; ++j)
        o[(size_t)(n0 + ty + j * 8) * CDIM + k0 + tx] = (short)f2bf(t[tx][ty + j * 8]);
}

// ---------------------------------------------------------------------------
// 128x128-tile GEMM, BK=32, K=1024, 256 threads (4 waves, 2x2), dbuf LDS,
// T3-min pipeline. MODE 0: fused QKV; MODE 1: O-proj. (unchanged)
// ---------------------------------------------------------------------------
template <int MODE, int GN>
__global__ __launch_bounds__(256) void gemm128(const short* __restrict__ A,
                                               const short* __restrict__ Bt,
                                               const float* __restrict__ b0,
                                               const float* __restrict__ b1,
                                               const float* __restrict__ b2,
                                               unsigned short* __restrict__ QKout,
                                               unsigned short* __restrict__ Vout,
                                               float* __restrict__ Fout) {
    __shared__ char lds[32768];
    char* AlB0 = lds;
    char* BlB0 = lds + 16384;

    const int tid = threadIdx.x, lane = tid & 63, w = tid >> 6;
    const int g = lane >> 4, t16 = lane & 15;
    const int wr = w >> 1, wc = w & 1;

    const int f = blockIdx.x;
    const int xcd = f & 7, i = f >> 3;
    const int mt = xcd * 8 + i / GN, nt = i % GN;
    const int tm = mt * 128, tn = nt * 128;
    const int part = tn >> 10;
    const int tnp = tn & 1023;

    const int c0 = tid, c1 = 256 + tid;
    const int r0 = c0 >> 2, r1 = c1 >> 2;
    const int k0c = (c0 & 3) ^ ((r0 >> 1) & 3);
    const int k1c = (c1 & 3) ^ ((r1 >> 1) & 3);
    const short* a0 = A + (size_t)(tm + r0) * 1024 + k0c * 8;
    const short* a1 = A + (size_t)(tm + r1) * 1024 + k1c * 8;
    const short* bp0 = Bt + (size_t)(tn + r0) * 1024 + k0c * 8;
    const short* bp1 = Bt + (size_t)(tn + r1) * 1024 + k1c * 8;

    int aoff[4], boff[4];
#pragma unroll
    for (int mi = 0; mi < 4; ++mi) {
        int row = wr * 64 + mi * 16 + t16;
        aoff[mi] = row * 64 + ((g ^ ((row >> 1) & 3)) << 4);
    }
#pragma unroll
    for (int ni = 0; ni < 4; ++ni) {
        int row = wc * 64 + ni * 16 + t16;
        boff[ni] = row * 64 + ((g ^ ((row >> 1) & 3)) << 4);
    }

    f32x4 acc[4][4];
#pragma unroll
    for (int mi = 0; mi < 4; ++mi)
#pragma unroll
        for (int ni = 0; ni < 4; ++ni) acc[mi][ni] = zero4();

#define STAGE(kt_, bb_)                                                   \
    do {                                                                  \
        int off_ = (kt_) * 32;                                            \
        char* al_ = AlB0 + (bb_) * 8192;                                  \
        char* bl_ = BlB0 + (bb_) * 8192;                                  \
        gload16(a0 + off_, al_ + tid * 16);                               \
        gload16(a1 + off_, al_ + 4096 + tid * 16);                        \
        gload16(bp0 + off_, bl_ + tid * 16);                              \
        gload16(bp1 + off_, bl_ + 4096 + tid * 16);                       \
    } while (0)

    STAGE(0, 0);
    __syncthreads();

#pragma unroll 2
    for (int kt = 0; kt < 32; ++kt) {
        const int buf = kt & 1;
        if (kt + 1 < 32) STAGE(kt + 1, buf ^ 1);
        const char* al = AlB0 + buf * 8192;
        const char* bl = BlB0 + buf * 8192;
        bhalf8 af[4], bfr[4];
#pragma unroll
        for (int mi = 0; mi < 4; ++mi) af[mi] = *(const bhalf8*)(al + aoff[mi]);
#pragma unroll
        for (int ni = 0; ni < 4; ++ni) bfr[ni] = *(const bhalf8*)(bl + boff[ni]);
        __builtin_amdgcn_s_setprio(1);
#pragma unroll
        for (int mi = 0; mi < 4; ++mi)
#pragma unroll
            for (int ni = 0; ni < 4; ++ni)
                acc[mi][ni] = MFMA(af[mi], bfr[ni], acc[mi][ni]);
        __builtin_amdgcn_s_setprio(0);
        __syncthreads();
    }
#undef STAGE

    if (MODE == 0 && part == 2) {
#pragma unroll
        for (int mi = 0; mi < 4; ++mi)
#pragma unroll
            for (int ni = 0; ni < 4; ++ni) {
                int col_l = wc * 64 + ni * 16 + t16;
                float bias = b2[tnp + col_l];
#pragma unroll
                for (int r = 0; r < 4; ++r) {
                    int row_l = wr * 64 + mi * 16 + g * 4 + r;
                    int byte = col_l * 256 + ((row_l * 2) ^ ((col_l & 7) << 4));
                    *(unsigned short*)(lds + byte) = f2bf(acc[mi][ni][r] + bias);
                }
            }
        __syncthreads();
#pragma unroll
        for (int p = 0; p < 8; ++p) {
            int lin = p * 4096 + tid * 16;
            int rv = lin >> 8;
            int inrow = lin & 255;
            int phys = rv * 256 + (inrow ^ ((rv & 7) << 4));
            bhalf8 val = *(const bhalf8*)(lds + phys);
            int n_g = tnp + rv;
            int hh = n_g >> 6, d = n_g & 63;
            int m = tm + (inrow >> 1);
            int bi = m >> 11, t0 = m & 2047;
            *(bhalf8*)(Vout + (((size_t)((bi * NHEAD + hh) * HDIM + d)) << 11) + t0) = val;
        }
    } else {
#pragma unroll
        for (int mi = 0; mi < 4; ++mi)
#pragma unroll
            for (int ni = 0; ni < 4; ++ni) {
                int col_l = wc * 64 + ni * 16 + t16;
                float bias = 0.f;
                if (MODE == 0) bias = (part == 0 ? b0 : b1)[tnp + col_l];
#pragma unroll
                for (int r = 0; r < 4; ++r) {
                    int row_l = wr * 64 + mi * 16 + g * 4 + r;
                    float v = acc[mi][ni][r] + bias;
                    if (MODE == 0 && part == 0) v *= QSCALE;
                    int byte = row_l * 256 + ((col_l * 2) ^ (((row_l >> 2) & 3) << 5));
                    *(unsigned short*)(lds + byte) = f2bf(v);
                }
            }
        __syncthreads();
#pragma unroll
        for (int p = 0; p < 8; ++p) {
            int lin = p * 4096 + tid * 16;
            int row_l = lin >> 8;
            int inrow = lin & 255;
            int phys = row_l * 256 + ((inrow & ~31) ^ (((row_l >> 2) & 3) << 5)) + (inrow & 31);
            bhalf8 val = *(const bhalf8*)(lds + phys);
            int col0 = inrow >> 1;
            int m = tm + row_l;
            if (MODE == 1) {
                int n_g = tn + col0;
                float* op = Fout + (size_t)m * 1024 + n_g;
                float4 o0, o1;
                o0.x = bf2f((unsigned short)val[0]) + b0[n_g + 0];
                o0.y = bf2f((unsigned short)val[1]) + b0[n_g + 1];
                o0.z = bf2f((unsigned short)val[2]) + b0[n_g + 2];
                o0.w = bf2f((unsigned short)val[3]) + b0[n_g + 3];
                o1.x = bf2f((unsigned short)val[4]) + b0[n_g + 4];
                o1.y = bf2f((unsigned short)val[5]) + b0[n_g + 5];
                o1.z = bf2f((unsigned short)val[6]) + b0[n_g + 6];
                o1.w = bf2f((unsigned short)val[7]) + b0[n_g + 7];
                *(float4*)(op) = o0;
                *(float4*)(op + 4) = o1;
            } else {
                int n_g = tnp + col0;
                int bi = m >> 11, t = m & 2047;
                int hh = n_g >> 6, d0 = n_g & 63;
                *(bhalf8*)(QKout +
                           (((size_t)((part * 64 + bi * NHEAD + hh) * SEQ + t)) << 6) + d0) = val;
            }
        }
    }
}

// ---------------------------------------------------------------------------
// Flash attention, causal, double-buffered, swapped QK^T, fixed-reference
// softmax (native v_exp_f32), l via ones-MFMA. BRANCH-STATIC buffers: the
// kv loop branches on buf so each side addresses compile-time-distinct LDS
// arrays -> all swizzled byte offsets are loop-invariant and hoisted.
// 64-row q-tiles paired s <-> 31-s (33 kv-tiles/block), 1024 blocks (4/CU).
// ---------------------------------------------------------------------------
__global__ __launch_bounds__(256) void attn_kernel(const short* __restrict__ Q,
                                                   const short* __restrict__ K,
                                                   const short* __restrict__ V,
                                                   unsigned short* __restrict__ ctx) {
    __shared__ short Kl0[64 * 64];
    __shared__ short Kl1[64 * 64];
    __shared__ short Vl0[64 * 64];
    __shared__ short Vl1[64 * 64];
    __shared__ short Pl[4][16 * 64];

    const int tid = threadIdx.x, lane = tid & 63, w = tid >> 6;
    const int g = lane >> 4, t16 = lane & 15;

    // 1024 blocks: XCD-chunk swizzle (128 consecutive per XCD = 8 full bh)
    int orig = blockIdx.x;
    int swz = (orig & 7) * 128 + (orig >> 3);
    const int bh = swz >> 4;      // 0..63
    const int sp = swz & 15;      // pair slot 0..15

    const short* Qh = Q + ((size_t)bh << 17);
    const short* Kh = K + ((size_t)bh << 17);
    const short* Vh = V + ((size_t)bh << 17);   // [D][T]

    // hoisted swizzled staging offsets (shorts) + LDS dest offsets (bytes)
    int koff[2], voff[2], ldst[2];
#pragma unroll
    for (int it = 0; it < 2; ++it) {
        int c = it * 256 + tid;
        int srow = c >> 3;
        int dc = (c & 7) ^ (srow & 7);
        koff[it] = (srow << 6) + dc * 8;
        voff[it] = (srow << 11) + dc * 8;
        ldst[it] = it * 4096 + w * 1024;
    }

#define STAGE(kv_, KA_, VA_)                                                  \
    do {                                                                      \
        gload16(Kh + koff[0] + ((kv_) << 12), (char*)(KA_) + ldst[0]);        \
        gload16(Kh + koff[1] + ((kv_) << 12), (char*)(KA_) + ldst[1]);        \
        gload16(Vh + voff[0] + ((kv_) << 6), (char*)(VA_) + ldst[0]);         \
        gload16(Vh + voff[1] + ((kv_) << 6), (char*)(VA_) + ldst[1]);         \
    } while (0)

#define TILE(KA_, VA_)                                                        \
    do {                                                                      \
        f32x4 lg[4];                                                          \
        __builtin_amdgcn_s_setprio(1);                                        \
        _Pragma("unroll") for (int cb = 0; cb < 4; ++cb) {                    \
            int s_ = cb * 16 + t16;                                           \
            int sw_ = (s_ & 7) << 4;                                          \
            const char* rowp = (const char*)(KA_) + s_ * 128;                 \
            bhalf8 k0 = *(const bhalf8*)(rowp + ((g * 16) ^ sw_));            \
            bhalf8 k1 = *(const bhalf8*)(rowp + ((64 + g * 16) ^ sw_));       \
            f32x4 z = zero4();                                                \
            z = MFMA(k0, qf0, z);                                             \
            z = MFMA(k1, qf1, z);                                             \
            lg[cb] = z;                                                       \
        }                                                                     \
        __builtin_amdgcn_s_setprio(0);                                        \
        if (kv == qti) {                                                      \
            int rowl = w * 16 + t16;                                          \
            _Pragma("unroll") for (int cb = 0; cb < 4; ++cb) {                \
                int key0 = cb * 16 + g * 4;                                   \
                _Pragma("unroll") for (int r = 0; r < 4; ++r)                 \
                    if (key0 + r > rowl) lg[cb][r] = -1e30f;                  \
            }                                                                 \
        }                                                                     \
        {                                                                     \
            int rowbyte = t16 * 128;                                          \
            _Pragma("unroll") for (int cb = 0; cb < 4; ++cb) {                \
                float e0 = exp2n(lg[cb][0]);                                  \
                float e1 = exp2n(lg[cb][1]);                                  \
                float e2 = exp2n(lg[cb][2]);                                  \
                float e3 = exp2n(lg[cb][3]);                                  \
                uint2 wv;                                                     \
                wv.x = pkbf16(e0, e1);                                        \
                wv.y = pkbf16(e2, e3);                                        \
                int byte = (rowbyte + cb * 32 + g * 8) ^ swb;                 \
                *(uint2*)((char*)Pl[w] + byte) = wv;                          \
            }                                                                 \
        }                                                                     \
        __builtin_amdgcn_s_setprio(1);                                        \
        _Pragma("unroll") for (int kk = 0; kk < 2; ++kk) {                    \
            bhalf8 vf[4];                                                     \
            _Pragma("unroll") for (int db = 0; db < 4; ++db) {                \
                int d = db * 16 + t16;                                        \
                int vbyte = d * 128 + ((kk * 64 + g * 16) ^ ((d & 7) << 4));  \
                vf[db] = *(const bhalf8*)((const char*)(VA_) + vbyte);        \
            }                                                                 \
            int abyte = (t16 * 128 + kk * 64 + g * 16) ^ swb;                 \
            bhalf8 pa = *(const bhalf8*)((const char*)Pl[w] + abyte);         \
            accl = MFMA(pa, ones, accl);                                      \
            _Pragma("unroll") for (int db = 0; db < 4; ++db)                  \
                acc[db] = MFMA(pa, vf[db], acc[db]);                          \
        }                                                                     \
        __builtin_amdgcn_s_setprio(0);                                        \
    } while (0)

    const int b = bh >> 4, hh = bh & 15;
    const int swb = (t16 & 7) << 4;

    bhalf8 ones;
#pragma unroll
    for (int q = 0; q < 8; ++q) ones[q] = (short)0x3F80;   // bf16 1.0

    int buf = 0;
    STAGE(0, Kl0, Vl0);   // phase-0 tile 0

    for (int ph = 0; ph < 2; ++ph) {
        const int qti = (ph == 0) ? (31 - sp) : sp;
        const int qbase = qti * 64;
        const int ntile = qti + 1;

        // Q B-frags: col=t16 -> q = qbase + w*16 + t16; k = kk*32+g*8+j
        bhalf8 qf0, qf1;
        {
            const short* qp = Qh + ((size_t)(qbase + w * 16 + t16) << 6) + g * 8;
            qf0 = *(const bhalf8*)(qp);
            qf1 = *(const bhalf8*)(qp + 32);
        }

        f32x4 acc[4];   // [db]: q = g*4+r, d = db*16+t16
        f32x4 accl;     // l row-sums: q = g*4+r (all 16 cols identical)
#pragma unroll
        for (int i = 0; i < 4; ++i) acc[i] = zero4();
        accl = zero4();

        __syncthreads();   // staged tile 0 ready (drains vmcnt)

        for (int kv = 0; kv < ntile; ++kv) {
            bool pre = (kv + 1 < ntile);
            if (buf == 0) {
                if (pre) STAGE(kv + 1, Kl1, Vl1);
                TILE(Kl0, Vl0);
            } else {
                if (pre) STAGE(kv + 1, Kl0, Vl0);
                TILE(Kl1, Vl1);
            }
            __syncthreads();
            buf ^= 1;
        }

        // prefetch phase-1 tile 0 into the free buffer (hides under epilogue)
        if (ph == 0) {
            if (buf == 0) STAGE(0, Kl0, Vl0);
            else          STAGE(0, Kl1, Vl1);
        }

        // ---- normalize (l in-lane, same layout as acc) + write ctx ----
#pragma unroll
        for (int r = 0; r < 4; ++r) {
            float inv = 1.f / accl[r];
            int t = qbase + w * 16 + g * 4 + r;
            size_t rowoff = (((size_t)(b * SEQ + t)) << 10) + hh * 64;
#pragma unroll
            for (int db = 0; db < 4; ++db)
                ctx[rowoff + db * 16 + t16] = f2bf(acc[db][r] * inv);
        }
    }
#undef TILE
#undef STAGE
}

// ---------------------------------------------------------------------------
// launch
// ---------------------------------------------------------------------------
extern "C" void kernel_launch(void* const* d_in, const int* in_sizes, int n_in,
                              void* d_out, int out_size, void* d_ws, size_t ws_size,
                              hipStream_t stream) {
    const float* x  = (const float*)d_in[0];
    const float* Wq = (const float*)d_in[1];
    const float* bq = (const float*)d_in[2];
    const float* Wk = (const float*)d_in[3];
    const float* bk = (const float*)d_in[4];
    const float* Wv = (const float*)d_in[5];
    const float* bv = (const float*)d_in[6];
    const float* Wo = (const float*)d_in[7];
    const float* bo = (const float*)d_in[8];

    char* ws = (char*)d_ws;
    short* x16 = (short*)(ws);                                // 16 MB
    short* Wt  = (short*)(ws + (size_t)16 * 1024 * 1024);     // q,k,v,o 2MB each
    short* Wot = Wt + (size_t)3 * CDIM * CDIM;
    short* Qb  = (short*)(ws + (size_t)24 * 1024 * 1024);     // 32 MB Q||K
    short* Vb  = (short*)(ws + (size_t)56 * 1024 * 1024);     // 16 MB [BH][D][T]
    short* Ctx = (short*)(ws + (size_t)72 * 1024 * 1024);     // 16 MB [M][C]

    cast_x_kernel<<<dim3(MTOT * CDIM / 8 / 256), dim3(256), 0, stream>>>(
        x, x16, MTOT * CDIM / 8);
    wtrans_kernel<<<dim3(32, 32, 4), dim3(32, 8), 0, stream>>>(Wq, Wk, Wv, Wo, Wt);

    // fused QKV projection: N = 3072 (Wq||Wk||Wv rows), 1536 blocks (6/CU)
    gemm128<0, 24><<<dim3(1536), dim3(256), 0, stream>>>(
        x16, Wt, bq, bk, bv, (unsigned short*)Qb, (unsigned short*)Vb, nullptr);

    // attention: 1024 paired blocks (K part = Qb + 64*SEQ*HDIM)
    attn_kernel<<<dim3(1024), dim3(256), 0, stream>>>(
        Qb, Qb + (size_t)64 * SEQ * HDIM, Vb, (unsigned short*)Ctx);

    // output projection -> fp32 d_out, 512 blocks (2/CU)
    gemm128<1, 8><<<dim3(512), dim3(256), 0, stream>>>(
        Ctx, Wot, bo, nullptr, nullptr, nullptr, nullptr, (float*)d_out);
}